// Round 18
// baseline (270.000 us; speedup 1.0000x reference)
//
#include <hip/hip_runtime.h>

typedef short short8  __attribute__((ext_vector_type(8)));
typedef float f32x4   __attribute__((ext_vector_type(4)));
typedef float f32x16  __attribute__((ext_vector_type(16)));

#define MFMA32(A,B,C) __builtin_amdgcn_mfma_f32_32x32x16_bf16((A),(B),(C),0,0,0)

__device__ __forceinline__ short bf16bits(float f){
  return (short)__builtin_bit_cast(unsigned short, static_cast<__bf16>(f));
}

// exp(s*0.125 - 8) = exp2(s*0.125*log2e - 8*log2e): one v_fma + v_exp.
// Region mask folded into BIAS: -3e38 -> exp2 == 0 exactly.
#define EXP_SCORE(s, BIAS) __builtin_amdgcn_exp2f(__builtin_fmaf((s), 0.18033688011112042f, (BIAS)))
#define EXP_C2 (-11.541560327111707f)

// ---------------- fused preprocessing ----------------
// blocks [0,220): mask preprocessing  (region_masks -> allowed bits)
// blocks [220,988): K/V repack to bf16 for the 32x32x16 MFMA path.
// All fragment chunks are 1KB = 64 lanes x 16B, lane l at offset l*16
// (fully-coalesced global_load_dwordx4 by construction).
//   K chunk (kc=key/32, f=d/16): lane = ((d>>3)&1)*32 + (key&31),
//     elem j = d&7  -> holds K[key][d = f*16 + 8*hi + j].
//   V chunk (kc, dblk=d/32, kh): key slot sigma-permuted so the score
//     MFMA's C register file IS the PV B-operand (no P anywhere):
//     C row formula row=(r&3)+8*(r>>2)+4*hi  =>  slot (kh,hi,e) must hold
//     key kappa = 16*kh + (e&3) + 8*(e>>2) + 4*hi. Inverse (given kappa):
//     kh=kappa>>4; rem=kappa&15; hi=(rem>>2)&1; e=(rem&3)+4*(rem>>3).
// (Layouts verified on hardware in rounds 14-17: passed, same absmax.)
__global__ __launch_bounds__(256) void prep_kernel(const float* __restrict__ rm,
                                                   const float* __restrict__ k,
                                                   const float* __restrict__ v,
                                                   const float* __restrict__ rk,
                                                   const float* __restrict__ rv,
                                                   unsigned* __restrict__ allowed,
                                                   unsigned short* __restrict__ Kb,
                                                   unsigned short* __restrict__ VT){
  const int bid = blockIdx.x;
  if (bid < 220){
    int s = bid*256 + threadIdx.x;
    if (s >= 56320) return;
    int t = s / 3520;
    int rem = s - t*3520;
    int i = rem / 80;
    int j = rem - i*80;
    int y = 2*i, x = 2*j;
    bool bin[2];
    #pragma unroll
    for (int r=0;r<2;r++){
      const float* base = rm + (size_t)r*121*88*160;
      float acc;
      if (t == 0){
        const float* p0 = base + (size_t)(0*88 + y)*160 + x;
        acc = 0.25f*(p0[0]+p0[1]+p0[160]+p0[161]);
      } else {
        const float* pa = base + (size_t)((8*t-4)*88 + y)*160 + x;
        const float* pb = base + (size_t)((8*t-3)*88 + y)*160 + x;
        acc = 0.125f*(pa[0]+pa[1]+pa[160]+pa[161] + pb[0]+pb[1]+pb[160]+pb[161]);
      }
      bin[r] = acc > 0.5f;
    }
    unsigned bits = (bin[0]||bin[1]) ? 0u : 1u;
    if (bin[0]) bits |= 2u;
    if (bin[1]) bits |= 4u;
    allowed[s] = bits;
  } else {
    int idx = (bid-220)*256 + threadIdx.x;   // over 3*128*8*64 = 196608
    if (idx >= 3*128*8*64) return;
    int d   = idx & 63;
    int h   = (idx >> 6) & 7;
    int p   = (idx >> 9) & 127;
    int seg = idx >> 16;
    int low = idx & 65535;                   // (p*8+h)*64+d
    float kv_, vv_;
    if (seg == 0){ kv_ = k[low];                          vv_ = v[low]; }
    else         { kv_ = rk[(size_t)(seg-1)*65536 + low]; vv_ = rv[(size_t)(seg-1)*65536 + low]; }
    const int kk = seg*128 + p;              // key index within head, 0..383
    // K fragment placement
    {
      const int f  = d >> 4, hi = (d >> 3) & 1, j = d & 7;
      Kb[(size_t)h*24576 + ((kk>>5)*4 + f)*512
         + (hi*32 + (kk&31))*8 + j] = (unsigned short)bf16bits(kv_);
    }
    // V fragment placement (sigma-permuted key slot)
    {
      const int kap = kk & 31;
      const int kh  = kap >> 4, rem = kap & 15;
      const int hi  = (rem >> 2) & 1;
      const int e   = (rem & 3) + 4*(rem >> 3);
      const int dblk = d >> 5;
      VT[(size_t)h*24576 + ((kk>>5)*4 + dblk*2 + kh)*512
         + (hi*32 + (d&31))*8 + e] = (unsigned short)bf16bits(vv_);
    }
  }
}

// ---------------- fused regional+base attention, deep-prefetch path ----------
// ROUND 18: r17's double-buffer only half-materialized (VGPR 120): the
// allocator's default budget for 256-thread blocks is 512/4 = 128 VGPRs
// (4 waves/SIMD target), but full dbuf needs ~154. Measured effective
// residency has been ~1.6 waves/SIMD across rounds 14-17, so targeting 4
// wastes the register file for nothing. amdgpu_waves_per_eu(1,2): min=1
// grants a 512-reg budget, max=2 is truthful (>= measured residency).
// With the budget: TRIPLE-buffered K/V register prefetch (A/B/C), loads
// issued 3-ahead-of-consume -> 2 full chunks (~1300cy) of latency cover,
// vs the ~600cy/chunk exposed wait that dominates the 12.8us wave life.
// Live set ~190 VGPR -> 2 waves/SIMD. No LDS, no barrier: waves fully
// independent (r16). sigma-permuted V: score C regs ARE the PV B-operand.
__global__ __launch_bounds__(256)
__attribute__((amdgpu_waves_per_eu(1, 2)))
void attn_kernel(const float* __restrict__ q,
                 const unsigned* __restrict__ allowed,
                 const unsigned short* __restrict__ Kb,
                 const unsigned short* __restrict__ VT,
                 float* __restrict__ out){
  const int h    = blockIdx.y;
  const int wave = threadIdx.x >> 6;
  const int lane = threadIdx.x & 63;
  const int qc   = lane & 31;        // query col
  const int hi   = lane >> 5;        // lane half

  const int s = blockIdx.x*128 + wave*32 + qc;

  const char* kgf = (const char*)Kb + (size_t)h*49152 + lane*16;  // K frags (L2)
  const char* vgf = (const char*)VT + (size_t)h*49152 + lane*16;  // V frags (L2)

  // ---- q + mask loads issue first (oldest in vmcnt order)
  const unsigned ab = allowed[s];
  const float* qp = q + ((size_t)s*8 + h)*64 + hi*8;
  f32x4 qa0 = *(const f32x4*)(qp);      f32x4 qb0 = *(const f32x4*)(qp+4);
  f32x4 qa1 = *(const f32x4*)(qp+16);   f32x4 qb1 = *(const f32x4*)(qp+20);
  f32x4 qa2 = *(const f32x4*)(qp+32);   f32x4 qb2 = *(const f32x4*)(qp+36);
  f32x4 qa3 = *(const f32x4*)(qp+48);   f32x4 qb3 = *(const f32x4*)(qp+52);

  // ---- triple-buffered K/V fragment prefetch (named regs, compile-time)
  short8 kA0,kA1,kA2,kA3, vA0,vA1,vA2,vA3;
  short8 kB0,kB1,kB2,kB3, vB0,vB1,vB2,vB3;
  short8 kC0,kC1,kC2,kC3, vC0,vC1,vC2,vC3;
#define LOAD_X(P, kc)                                                 \
  k##P##0 = *(const short8*)(kgf + ((kc)*4+0)*1024);                  \
  k##P##1 = *(const short8*)(kgf + ((kc)*4+1)*1024);                  \
  k##P##2 = *(const short8*)(kgf + ((kc)*4+2)*1024);                  \
  k##P##3 = *(const short8*)(kgf + ((kc)*4+3)*1024);                  \
  v##P##0 = *(const short8*)(vgf + ((kc)*4+0)*1024);                  \
  v##P##1 = *(const short8*)(vgf + ((kc)*4+1)*1024);                  \
  v##P##2 = *(const short8*)(vgf + ((kc)*4+2)*1024);                  \
  v##P##3 = *(const short8*)(vgf + ((kc)*4+3)*1024);                  \
  __builtin_amdgcn_sched_barrier(0x38F);  /* pin VMEM issue order */

// one 32-key chunk from buffer P: 4 score MFMAs -> exp2(fma, mask in
// bias) -> pf0/pf1 (PV B-frags via sigma) -> 4 PV MFMAs
#define CHUNK_X(P, LSUM, BIAS, A0, A1)                                \
  {                                                                   \
    f32x16 sa = {0,0,0,0,0,0,0,0,0,0,0,0,0,0,0,0};                    \
    sa = MFMA32(k##P##0, qf0, sa);                                    \
    sa = MFMA32(k##P##1, qf1, sa);                                    \
    sa = MFMA32(k##P##2, qf2, sa);                                    \
    sa = MFMA32(k##P##3, qf3, sa);                                    \
    short8 pf0, pf1;                                                  \
    _Pragma("unroll")                                                 \
    for (int r=0;r<8;r++){                                            \
      float e0 = EXP_SCORE(sa[r],   BIAS); LSUM += e0; pf0[r] = bf16bits(e0); \
      float e1 = EXP_SCORE(sa[8+r], BIAS); LSUM += e1; pf1[r] = bf16bits(e1); \
    }                                                                 \
    A0 = MFMA32(v##P##0, pf0, A0);                                    \
    A0 = MFMA32(v##P##1, pf1, A0);                                    \
    A1 = MFMA32(v##P##2, pf0, A1);                                    \
    A1 = MFMA32(v##P##3, pf1, A1);                                    \
  }

  // ---- prologue: fill all three buffers (chunks 0,1,2 in flight)
  LOAD_X(A, 0);
  LOAD_X(B, 1);
  LOAD_X(C, 2);

  // ---- q -> bf16 frags (overlaps the in-flight K/V stream)
  short8 qf0, qf1, qf2, qf3;
  #pragma unroll
  for (int j=0;j<4;j++){
    qf0[j]=bf16bits(qa0[j]); qf0[4+j]=bf16bits(qb0[j]);
    qf1[j]=bf16bits(qa1[j]); qf1[4+j]=bf16bits(qb1[j]);
    qf2[j]=bf16bits(qa2[j]); qf2[4+j]=bf16bits(qb2[j]);
    qf3[j]=bf16bits(qa3[j]); qf3[4+j]=bf16bits(qb3[j]);
  }

  const float bias1 = ((ab>>1)&1u) ? EXP_C2 : -3.0e38f;  // region 0 (chunks 4-7)
  const float bias2 = ((ab>>2)&1u) ? EXP_C2 : -3.0e38f;  // region 1 (chunks 8-11)

  float lb = 0.f, lr = 0.f;
  f32x16 aB0 = {0,0,0,0,0,0,0,0,0,0,0,0,0,0,0,0};
  f32x16 aB1 = {0,0,0,0,0,0,0,0,0,0,0,0,0,0,0,0};
  f32x16 aR0 = {0,0,0,0,0,0,0,0,0,0,0,0,0,0,0,0};
  f32x16 aR1 = {0,0,0,0,0,0,0,0,0,0,0,0,0,0,0,0};

  // ---- steady state: consume one buffer, immediately refill it 3 ahead
  CHUNK_X(A, lb, EXP_C2, aB0, aB1);  LOAD_X(A, 3);    // base (keys 0-127)
  CHUNK_X(B, lb, EXP_C2, aB0, aB1);  LOAD_X(B, 4);
  CHUNK_X(C, lb, EXP_C2, aB0, aB1);  LOAD_X(C, 5);
  CHUNK_X(A, lb, EXP_C2, aB0, aB1);  LOAD_X(A, 6);
  CHUNK_X(B, lr, bias1,  aR0, aR1);  LOAD_X(B, 7);    // region 0 (128-255)
  CHUNK_X(C, lr, bias1,  aR0, aR1);  LOAD_X(C, 8);
  CHUNK_X(A, lr, bias1,  aR0, aR1);  LOAD_X(A, 9);
  CHUNK_X(B, lr, bias1,  aR0, aR1);  LOAD_X(B, 10);
  CHUNK_X(C, lr, bias2,  aR0, aR1);  LOAD_X(C, 11);   // region 1 (256-383)
  CHUNK_X(A, lr, bias2,  aR0, aR1);
  CHUNK_X(B, lr, bias2,  aR0, aR1);
  CHUNK_X(C, lr, bias2,  aR0, aR1);

  // ---- row sums: lanes l and l^32 hold the two key-halves of one query
  lb += __shfl_xor(lb, 32);
  lr += __shfl_xor(lr, 32);

  const float invb = 0.5f/lb;
  const float lreg = ((ab&1u)? lb : 0.f) + lr;
  const float invr = 0.5f/lreg;
  const float cA   = invb + ((ab&1u)? invr : 0.f);

  // ---- combine and store:
  // reg R=g*4+r of dblk -> d = dblk*32 + 8*g + 4*hi + r  (16B f32x4 stores)
  float* ob = out + (size_t)s*512 + h*64 + hi*4;
  #pragma unroll
  for (int g=0; g<4; ++g){
    f32x4 o0, o1;
    #pragma unroll
    for (int r=0;r<4;r++){
      o0[r] = aB0[g*4+r]*cA + aR0[g*4+r]*invr;
      o1[r] = aB1[g*4+r]*cA + aR1[g*4+r]*invr;
    }
    *(f32x4*)(ob + g*8)      = o0;   // dblk 0
    *(f32x4*)(ob + 32 + g*8) = o1;   // dblk 1
  }
}

extern "C" void kernel_launch(void* const* d_in, const int* in_sizes, int n_in,
                              void* d_out, int out_size, void* d_ws, size_t ws_size,
                              hipStream_t stream) {
  const float* q  = (const float*)d_in[0];
  const float* k  = (const float*)d_in[1];
  const float* v  = (const float*)d_in[2];
  const float* rk = (const float*)d_in[3];
  const float* rv = (const float*)d_in[4];
  const float* rm = (const float*)d_in[5];
  float* out = (float*)d_out;

  char* ws = (char*)d_ws;
  unsigned*       allowed = (unsigned*)ws;                           // 56320*4   = 225280 B
  unsigned short* Kb      = (unsigned short*)(ws + 225280);          // 8*3*128*64*2 = 393216 B
  unsigned short* VT      = (unsigned short*)(ws + 225280 + 393216); // 393216 B

  prep_kernel<<<988, 256, 0, stream>>>(rm, k, v, rk, rv, allowed, Kb, VT);
  dim3 grid(440, 8);
  attn_kernel<<<grid, 256, 0, stream>>>(q, allowed, Kb, VT, out);
}